// Round 4
// baseline (1308.680 us; speedup 1.0000x reference)
//
#include <hip/hip_runtime.h>
#include <math.h>
#include <stdint.h>

#define DIM   1024
#define HID   4096
#define NE    8
#define NTOK  8192
#define MAXROWS 17408   // 16384 pairs + up to 8*127 tile padding
#define LB_W  0.01f

typedef unsigned short u16;
typedef unsigned int   u32;

typedef __bf16 bf16x8 __attribute__((ext_vector_type(8)));
typedef float  f32x4  __attribute__((ext_vector_type(4)));
typedef u16    u16x8  __attribute__((ext_vector_type(8)));

typedef const __attribute__((address_space(1))) void* gas_t;
typedef __attribute__((address_space(3))) void* las_t;

__device__ __forceinline__ u16 f2b(float f) {   // fp32 -> bf16 RNE
    union { float f; u32 i; } v; v.f = f;
    u32 u = v.i;
    return (u16)((u + 0x7FFFu + ((u >> 16) & 1u)) >> 16);
}

// ---------------------------------------------------------------- gate
// wave-per-token fp32 dot(1024x8), butterfly reduce, lane0 top-2+softmax.
// Also emits bf16 copy of x (xb) so GEMM1 can async-stage pure bf16.
__global__ __launch_bounds__(256)
void gate_kernel(const float* __restrict__ x, const float* __restrict__ gw,
                 const float* __restrict__ gb, u32* __restrict__ tokE,
                 float2* __restrict__ tokP, int* __restrict__ cnt,
                 float* __restrict__ eload, u16* __restrict__ xb)
{
    __shared__ float se[NE];
    __shared__ int   sc[NE];
    const int tid = threadIdx.x;
    if (tid < NE) { se[tid] = 0.f; sc[tid] = 0; }
    __syncthreads();
    const int lane = tid & 63, wid = tid >> 6;
    for (int j = 0; j < 8; ++j) {
        const int t = blockIdx.x * 32 + wid * 8 + j;
        float s[NE];
#pragma unroll
        for (int ee = 0; ee < NE; ++ee) s[ee] = 0.f;
        const float* xt = x + (size_t)t * DIM + lane * 16;
        u16 xc[16];
#pragma unroll
        for (int q = 0; q < 4; ++q) {
            const float4 xv = *(const float4*)(xt + q * 4);
            const float xf[4] = {xv.x, xv.y, xv.z, xv.w};
            xc[q * 4 + 0] = f2b(xv.x); xc[q * 4 + 1] = f2b(xv.y);
            xc[q * 4 + 2] = f2b(xv.z); xc[q * 4 + 3] = f2b(xv.w);
#pragma unroll
            for (int u = 0; u < 4; ++u) {
                const int d = lane * 16 + q * 4 + u;
                const float4 g0 = *(const float4*)(gw + d * 8);
                const float4 g1 = *(const float4*)(gw + d * 8 + 4);
                s[0] += xf[u] * g0.x; s[1] += xf[u] * g0.y;
                s[2] += xf[u] * g0.z; s[3] += xf[u] * g0.w;
                s[4] += xf[u] * g1.x; s[5] += xf[u] * g1.y;
                s[6] += xf[u] * g1.z; s[7] += xf[u] * g1.w;
            }
        }
        u16* xbo = xb + (size_t)t * DIM + lane * 16;
        *(u16x8*)(xbo)     = *(const u16x8*)&xc[0];
        *(u16x8*)(xbo + 8) = *(const u16x8*)&xc[8];
#pragma unroll
        for (int ee = 0; ee < NE; ++ee) {
#pragma unroll
            for (int off = 32; off >= 1; off >>= 1)
                s[ee] += __shfl_xor(s[ee], off);
        }
        if (lane == 0) {
            float l[NE];
#pragma unroll
            for (int ee = 0; ee < NE; ++ee) l[ee] = s[ee] + gb[ee];
            int e0 = 0;
#pragma unroll
            for (int ee = 1; ee < NE; ++ee) if (l[ee] > l[e0]) e0 = ee;
            int e1 = (e0 == 0) ? 1 : 0;
#pragma unroll
            for (int ee = 0; ee < NE; ++ee)
                if (ee != e0 && l[ee] > l[e1]) e1 = ee;
            const float p0 = 1.f / (1.f + expf(l[e1] - l[e0]));  // l0>=l1: stable
            const float p1 = 1.f - p0;
            tokE[t] = (u32)e0 | ((u32)e1 << 16);
            tokP[t] = make_float2(p0, p1);
            atomicAdd(&se[e0], p0);
            atomicAdd(&se[e1], p1);
            atomicAdd(&sc[e0], 1);
            atomicAdd(&sc[e1], 1);
        }
    }
    __syncthreads();
    if (tid < NE) {
        atomicAdd(&eload[tid], se[tid]);
        atomicAdd(&cnt[tid], sc[tid]);
    }
}

// ---------------------------------------------------------- bucket offsets
__global__ void offsets_kernel(const int* __restrict__ cnt, int* __restrict__ offs,
                               int* __restrict__ rowtok, float* __restrict__ rowp)
{
    int c[NE], off[NE], cap[NE];
    int o = 0;
#pragma unroll
    for (int e = 0; e < NE; ++e) {
        c[e] = cnt[e];
        cap[e] = (c[e] + 127) & ~127;
        off[e] = o;
        o += cap[e];
    }
    if (threadIdx.x < NE) offs[threadIdx.x] = off[threadIdx.x];
    for (int e = 0; e < NE; ++e)
        for (int i = c[e] + (int)threadIdx.x; i < cap[e]; i += 64) {
            rowtok[off[e] + i] = 0;
            rowp[off[e] + i]   = 0.f;
        }
}

// ---------------------------------------------------------------- scatter
__global__ __launch_bounds__(256)
void scatter_kernel(const u32* __restrict__ tokE, const float2* __restrict__ tokP,
                    const int* __restrict__ offs, int* __restrict__ cnt2,
                    int* __restrict__ rowtok, float* __restrict__ rowp)
{
    __shared__ int lc[NE];
    __shared__ int lb[NE];
    const int tid = threadIdx.x;
    if (tid < NE) lc[tid] = 0;
    __syncthreads();
    const int t = blockIdx.x * 256 + tid;
    const u32 ep = tokE[t];
    const float2 p = tokP[t];
    const int e0 = (int)(ep & 0xFFFFu), e1 = (int)(ep >> 16);
    const int q0 = atomicAdd(&lc[e0], 1);
    const int q1 = atomicAdd(&lc[e1], 1);
    __syncthreads();
    if (tid < NE) lb[tid] = atomicAdd(&cnt2[tid], lc[tid]);
    __syncthreads();
    const int r0 = offs[e0] + lb[e0] + q0;
    rowtok[r0] = t; rowp[r0] = p.x;
    const int r1 = offs[e1] + lb[e1] + q1;
    rowtok[r1] = t; rowp[r1] = p.y;
}

// -------------------------------------------------------------- transpose
// fp32 [E][R][C] -> bf16 [E][C][R]  (weights K-major -> N-major for MFMA B)
__global__ __launch_bounds__(256)
void transpose_kernel(const float* __restrict__ in, u16* __restrict__ out,
                      int R, int C)
{
    __shared__ float tile[32][33];
    const int e = blockIdx.z;
    const float* pin = in + (size_t)e * R * C;
    u16* pout = out + (size_t)e * R * C;
    const int c0 = blockIdx.x * 32, r0 = blockIdx.y * 32;
#pragma unroll
    for (int i = 0; i < 4; ++i) {
        const int r = threadIdx.y + i * 8;
        tile[r][threadIdx.x] = pin[(size_t)(r0 + r) * C + c0 + threadIdx.x];
    }
    __syncthreads();
#pragma unroll
    for (int i = 0; i < 4; ++i) {
        const int r = threadIdx.y + i * 8;
        pout[(size_t)(c0 + r) * R + r0 + threadIdx.x] = f2b(tile[threadIdx.x][r]);
    }
}

// ------------------------------------------------------------------ GEMM1
// h[row] = gelu(xb[tok(row)] @ w1[e] + b1[e]).  m97 structure:
// global_load_lds width-16 staging, XOR-swizzled LDS slots (k8 ^= row&7)
// to turn the 16-way ds_read bank conflict into a free 2-way.
// Grid: x=mt (rows), y=nt, z=e  -> same-mt blocks land on one XCD (ids
// differ by 64 == 0 mod 8), so the shared A-tile is fetched once per XCD.
__global__ __launch_bounds__(256, 4)
void gemm1_kernel(const u16* __restrict__ xb, const u16* __restrict__ w1t,
                  const float* __restrict__ b1, const int* __restrict__ cnt,
                  const int* __restrict__ offs, const int* __restrict__ rowtok,
                  u16* __restrict__ h)
{
    const int e = blockIdx.z;
    const int ne = cnt[e];
    const int mt = blockIdx.x;
    if (mt * 128 >= ne) return;               // capacity grid, data-dependent exit
    const int nt = blockIdx.y;
    const int rowbase = offs[e] + mt * 128;

    __shared__ u16 lA[128 * 64];
    __shared__ u16 lB[128 * 64];

    const int tid = threadIdx.x;
    const int lane = tid & 63;
    const int wid = tid >> 6;

    const u16* wB = w1t + (size_t)e * HID * DIM + (size_t)nt * 128 * DIM;

    const u16* agp[4];
    const u16* bgp[4];
#pragma unroll
    for (int c = 0; c < 4; ++c) {
        const int lin = tid + c * 256;
        const int row = lin >> 3;
        const int k8 = (lin & 7) ^ (row & 7);     // LDS slot j holds chunk j^(row&7)
        const int tok = rowtok[rowbase + row];
        agp[c] = xb + (size_t)tok * DIM + k8 * 8;
        bgp[c] = wB + (size_t)row * DIM + k8 * 8;
    }

    f32x4 acc[4][4];
#pragma unroll
    for (int i = 0; i < 4; ++i)
#pragma unroll
        for (int j = 0; j < 4; ++j)
            acc[i][j] = (f32x4){0.f, 0.f, 0.f, 0.f};

    const int wm = (wid >> 1) * 64;
    const int wn = (wid & 1) * 64;
    const int rsub = lane & 15;               // row within 16-block
    const int sw = lane & 7;                  // = row&7 for all fragment rows
    const int cq = lane >> 4;                 // k-chunk quad offset

    for (int k0 = 0; k0 < DIM; k0 += 64) {
        __syncthreads();
#pragma unroll
        for (int c = 0; c < 4; ++c) {
            __builtin_amdgcn_global_load_lds((gas_t)(agp[c] + k0),
                (las_t)&lA[(tid + c * 256) * 8], 16, 0, 0);
            __builtin_amdgcn_global_load_lds((gas_t)(bgp[c] + k0),
                (las_t)&lB[(tid + c * 256) * 8], 16, 0, 0);
        }
        __syncthreads();
#pragma unroll
        for (int ks = 0; ks < 2; ++ks) {
            const int cc = ks * 4 + cq;       // global k-chunk within the 64-window
            const int js = (cc ^ sw) * 8;     // swizzled LDS slot offset (u16)
            bf16x8 av[4], bv[4];
#pragma unroll
            for (int f = 0; f < 4; ++f) {
                av[f] = *(const bf16x8*)&lA[(wm + f * 16 + rsub) * 64 + js];
                bv[f] = *(const bf16x8*)&lB[(wn + f * 16 + rsub) * 64 + js];
            }
#pragma unroll
            for (int i = 0; i < 4; ++i)
#pragma unroll
                for (int j = 0; j < 4; ++j)
                    acc[i][j] = __builtin_amdgcn_mfma_f32_16x16x32_bf16(
                        av[i], bv[j], acc[i][j], 0, 0, 0);
        }
    }

    // epilogue: C/D layout col=lane&15, row=(lane>>4)*4+reg (m89-verified)
    const int col = lane & 15;
    const int rq = (lane >> 4) * 4;
    const float* b1e = b1 + e * HID;
#pragma unroll
    for (int j = 0; j < 4; ++j) {
        const int hcol = nt * 128 + wn + j * 16 + col;
        const float bias = b1e[hcol];
#pragma unroll
        for (int i = 0; i < 4; ++i) {
            const int mrow = wm + i * 16 + rq;
#pragma unroll
            for (int r = 0; r < 4; ++r) {
                float v = acc[i][j][r] + bias;
                v = 0.5f * v * (1.f + erff(v * 0.70710678118f));   // exact gelu
                h[(size_t)(rowbase + mrow + r) * HID + hcol] = f2b(v);
            }
        }
    }
}

// ------------------------------------------------------------------ GEMM2
// (h[row] @ w2[e] + b2[e]) * p[row] -> atomicAdd fp32 directly into out.
__global__ __launch_bounds__(256, 4)
void gemm2_kernel(const u16* __restrict__ h, const u16* __restrict__ w2t,
                  const float* __restrict__ b2, const int* __restrict__ cnt,
                  const int* __restrict__ offs, const int* __restrict__ rowtok,
                  const float* __restrict__ rowp, float* __restrict__ outc)
{
    const int e = blockIdx.z;
    const int ne = cnt[e];
    const int mt = blockIdx.x;
    if (mt * 128 >= ne) return;
    const int nt = blockIdx.y;
    const int rowbase = offs[e] + mt * 128;

    __shared__ u16 lA[128 * 64];
    __shared__ u16 lB[128 * 64];

    const int tid = threadIdx.x;
    const int lane = tid & 63;
    const int wid = tid >> 6;

    const u16* wB = w2t + (size_t)e * DIM * HID + (size_t)nt * 128 * HID;

    const u16* agp[4];
    const u16* bgp[4];
#pragma unroll
    for (int c = 0; c < 4; ++c) {
        const int lin = tid + c * 256;
        const int row = lin >> 3;
        const int k8 = (lin & 7) ^ (row & 7);
        agp[c] = h  + (size_t)(rowbase + row) * HID + k8 * 8;
        bgp[c] = wB + (size_t)row * HID + k8 * 8;
    }

    f32x4 acc[4][4];
#pragma unroll
    for (int i = 0; i < 4; ++i)
#pragma unroll
        for (int j = 0; j < 4; ++j)
            acc[i][j] = (f32x4){0.f, 0.f, 0.f, 0.f};

    const int wm = (wid >> 1) * 64;
    const int wn = (wid & 1) * 64;
    const int rsub = lane & 15;
    const int sw = lane & 7;
    const int cq = lane >> 4;

    for (int k0 = 0; k0 < HID; k0 += 64) {
        __syncthreads();
#pragma unroll
        for (int c = 0; c < 4; ++c) {
            __builtin_amdgcn_global_load_lds((gas_t)(agp[c] + k0),
                (las_t)&lA[(tid + c * 256) * 8], 16, 0, 0);
            __builtin_amdgcn_global_load_lds((gas_t)(bgp[c] + k0),
                (las_t)&lB[(tid + c * 256) * 8], 16, 0, 0);
        }
        __syncthreads();
#pragma unroll
        for (int ks = 0; ks < 2; ++ks) {
            const int cc = ks * 4 + cq;
            const int js = (cc ^ sw) * 8;
            bf16x8 av[4], bv[4];
#pragma unroll
            for (int f = 0; f < 4; ++f) {
                av[f] = *(const bf16x8*)&lA[(wm + f * 16 + rsub) * 64 + js];
                bv[f] = *(const bf16x8*)&lB[(wn + f * 16 + rsub) * 64 + js];
            }
#pragma unroll
            for (int i = 0; i < 4; ++i)
#pragma unroll
                for (int j = 0; j < 4; ++j)
                    acc[i][j] = __builtin_amdgcn_mfma_f32_16x16x32_bf16(
                        av[i], bv[j], acc[i][j], 0, 0, 0);
        }
    }

    const int col = lane & 15;
    const int rq = (lane >> 4) * 4;
    const float* b2e = b2 + e * DIM;
    float biasv[4];
#pragma unroll
    for (int j = 0; j < 4; ++j)
        biasv[j] = b2e[nt * 128 + wn + j * 16 + col];
#pragma unroll
    for (int i = 0; i < 4; ++i) {
#pragma unroll
        for (int r = 0; r < 4; ++r) {
            const int rg = rowbase + wm + i * 16 + rq + r;
            const float p = rowp[rg];        // pad rows have p=0 -> adds 0
            const int tok = rowtok[rg];
            float* dst = outc + (size_t)tok * DIM + nt * 128 + wn + col;
#pragma unroll
            for (int j = 0; j < 4; ++j)
                atomicAdd(dst + j * 16, (acc[i][j][r] + biasv[j]) * p);
        }
    }
}

// ------------------------------------------------------------------ tail
__global__ void tail_kernel(const float* __restrict__ eload, float* __restrict__ out)
{
    if (threadIdx.x == 0) {
        float loss = 0.f;
        float le[NE];
#pragma unroll
        for (int e = 0; e < NE; ++e) {
            le[e] = eload[e] * (1.f / (float)NTOK);
            const float d = le[e] - 1.f / (float)NE;
            loss += d * d;
        }
        loss *= LB_W;
        out[(size_t)NTOK * DIM] = loss;
#pragma unroll
        for (int e = 0; e < NE; ++e)
            out[(size_t)NTOK * DIM + 1 + e] = le[e];
    }
}

// ------------------------------------------------------------------ launch
extern "C" void kernel_launch(void* const* d_in, const int* in_sizes, int n_in,
                              void* d_out, int out_size, void* d_ws, size_t ws_size,
                              hipStream_t stream)
{
    const float* x  = (const float*)d_in[0];
    const float* gw = (const float*)d_in[1];
    const float* gb = (const float*)d_in[2];
    const float* w1 = (const float*)d_in[3];
    const float* b1 = (const float*)d_in[4];
    const float* w2 = (const float*)d_in[5];
    const float* b2 = (const float*)d_in[6];
    float* out = (float*)d_out;
    char* ws = (char*)d_ws;

    // workspace layout (bytes), total ~281 MiB
    int*    cnt    = (int*)   (ws + 0);          // 32
    int*    cnt2   = (int*)   (ws + 32);         // 32
    int*    offs   = (int*)   (ws + 64);         // 32
    float*  eload  = (float*) (ws + 96);         // 32
    u32*    tokE   = (u32*)   (ws + 128);        // 32768
    float2* tokP   = (float2*)(ws + 32896);      // 65536
    int*    rowtok = (int*)   (ws + 98432);      // 69632
    float*  rowp   = (float*) (ws + 168064);     // 69632
    u16*    xb     = (u16*)   (ws + 237824);     // 16777216 (bf16 x)
    u16*    w1t    = (u16*)   (ws + 17015040);   // 67108864 (bf16)
    u16*    w2t    = (u16*)   (ws + 84123904);   // 67108864 (bf16)
    u16*    h      = (u16*)   (ws + 151232768);  // 142606336 (bf16)

    hipMemsetAsync(ws, 0, 128, stream);                                 // counters
    hipMemsetAsync(out, 0, (size_t)NTOK * DIM * sizeof(float), stream); // combine dst

    transpose_kernel<<<dim3(HID / 32, DIM / 32, NE), dim3(32, 8), 0, stream>>>(
        w1, w1t, DIM, HID);
    transpose_kernel<<<dim3(DIM / 32, HID / 32, NE), dim3(32, 8), 0, stream>>>(
        w2, w2t, HID, DIM);
    gate_kernel<<<NTOK / 32, 256, 0, stream>>>(x, gw, gb, tokE, tokP, cnt, eload, xb);
    offsets_kernel<<<1, 64, 0, stream>>>(cnt, offs, rowtok, rowp);
    scatter_kernel<<<NTOK / 256, 256, 0, stream>>>(tokE, tokP, offs, cnt2, rowtok, rowp);
    gemm1_kernel<<<dim3(64, HID / 128, NE), 256, 0, stream>>>(
        xb, w1t, b1, cnt, offs, rowtok, h);
    gemm2_kernel<<<dim3(64, DIM / 128, NE), 256, 0, stream>>>(
        h, w2t, b2, cnt, offs, rowtok, rowp, out);
    tail_kernel<<<1, 64, 0, stream>>>(eload, out);
}

// Round 5
// 855.057 us; speedup vs baseline: 1.5305x; 1.5305x over previous
//
#include <hip/hip_runtime.h>
#include <math.h>
#include <stdint.h>

#define DIM   1024
#define HID   4096
#define NE    8
#define NTOK  8192
#define MAXROWS 17408   // 16384 pairs + up to 8*127 tile padding
#define LB_W  0.01f

typedef unsigned short u16;
typedef unsigned int   u32;

typedef __bf16 bf16x8 __attribute__((ext_vector_type(8)));
typedef float  f32x4  __attribute__((ext_vector_type(4)));
typedef u16    u16x8  __attribute__((ext_vector_type(8)));

__device__ __forceinline__ u16 f2b(float f) {   // fp32 -> bf16 RNE
    union { float f; u32 i; } v; v.f = f;
    u32 u = v.i;
    return (u16)((u + 0x7FFFu + ((u >> 16) & 1u)) >> 16);
}

// ---------------------------------------------------------------- gate
// wave-per-token fp32 dot(1024x8), butterfly reduce, lane0 top-2+softmax.
// Also emits bf16 copy of x (xb) so GEMM1 stages pure bf16 (kills its cvt VALU).
__global__ __launch_bounds__(256)
void gate_kernel(const float* __restrict__ x, const float* __restrict__ gw,
                 const float* __restrict__ gb, u32* __restrict__ tokE,
                 float2* __restrict__ tokP, int* __restrict__ cnt,
                 float* __restrict__ eload, u16* __restrict__ xb)
{
    __shared__ float se[NE];
    __shared__ int   sc[NE];
    const int tid = threadIdx.x;
    if (tid < NE) { se[tid] = 0.f; sc[tid] = 0; }
    __syncthreads();
    const int lane = tid & 63, wid = tid >> 6;
    for (int j = 0; j < 8; ++j) {
        const int t = blockIdx.x * 32 + wid * 8 + j;
        float s[NE];
#pragma unroll
        for (int ee = 0; ee < NE; ++ee) s[ee] = 0.f;
        const float* xt = x + (size_t)t * DIM + lane * 16;
        u16 xc[16];
#pragma unroll
        for (int q = 0; q < 4; ++q) {
            const float4 xv = *(const float4*)(xt + q * 4);
            const float xf[4] = {xv.x, xv.y, xv.z, xv.w};
            xc[q * 4 + 0] = f2b(xv.x); xc[q * 4 + 1] = f2b(xv.y);
            xc[q * 4 + 2] = f2b(xv.z); xc[q * 4 + 3] = f2b(xv.w);
#pragma unroll
            for (int u = 0; u < 4; ++u) {
                const int d = lane * 16 + q * 4 + u;
                const float4 g0 = *(const float4*)(gw + d * 8);
                const float4 g1 = *(const float4*)(gw + d * 8 + 4);
                s[0] += xf[u] * g0.x; s[1] += xf[u] * g0.y;
                s[2] += xf[u] * g0.z; s[3] += xf[u] * g0.w;
                s[4] += xf[u] * g1.x; s[5] += xf[u] * g1.y;
                s[6] += xf[u] * g1.z; s[7] += xf[u] * g1.w;
            }
        }
        u16* xbo = xb + (size_t)t * DIM + lane * 16;
        *(u16x8*)(xbo)     = *(const u16x8*)&xc[0];
        *(u16x8*)(xbo + 8) = *(const u16x8*)&xc[8];
#pragma unroll
        for (int ee = 0; ee < NE; ++ee) {
#pragma unroll
            for (int off = 32; off >= 1; off >>= 1)
                s[ee] += __shfl_xor(s[ee], off);
        }
        if (lane == 0) {
            float l[NE];
#pragma unroll
            for (int ee = 0; ee < NE; ++ee) l[ee] = s[ee] + gb[ee];
            int e0 = 0;
#pragma unroll
            for (int ee = 1; ee < NE; ++ee) if (l[ee] > l[e0]) e0 = ee;
            int e1 = (e0 == 0) ? 1 : 0;
#pragma unroll
            for (int ee = 0; ee < NE; ++ee)
                if (ee != e0 && l[ee] > l[e1]) e1 = ee;
            const float p0 = 1.f / (1.f + expf(l[e1] - l[e0]));  // l0>=l1: stable
            const float p1 = 1.f - p0;
            tokE[t] = (u32)e0 | ((u32)e1 << 16);
            tokP[t] = make_float2(p0, p1);
            atomicAdd(&se[e0], p0);
            atomicAdd(&se[e1], p1);
            atomicAdd(&sc[e0], 1);
            atomicAdd(&sc[e1], 1);
        }
    }
    __syncthreads();
    if (tid < NE) {
        atomicAdd(&eload[tid], se[tid]);
        atomicAdd(&cnt[tid], sc[tid]);
    }
}

// ---------------------------------------------------------- bucket offsets
__global__ void offsets_kernel(const int* __restrict__ cnt, int* __restrict__ offs,
                               int* __restrict__ rowtok, float* __restrict__ rowp)
{
    int c[NE], off[NE], cap[NE];
    int o = 0;
#pragma unroll
    for (int e = 0; e < NE; ++e) {
        c[e] = cnt[e];
        cap[e] = (c[e] + 127) & ~127;
        off[e] = o;
        o += cap[e];
    }
    if (threadIdx.x < NE) offs[threadIdx.x] = off[threadIdx.x];
    for (int e = 0; e < NE; ++e)
        for (int i = c[e] + (int)threadIdx.x; i < cap[e]; i += 64) {
            rowtok[off[e] + i] = 0;
            rowp[off[e] + i]   = 0.f;
        }
}

// ---------------------------------------------------------------- scatter
__global__ __launch_bounds__(256)
void scatter_kernel(const u32* __restrict__ tokE, const float2* __restrict__ tokP,
                    const int* __restrict__ offs, int* __restrict__ cnt2,
                    int* __restrict__ rowtok, float* __restrict__ rowp)
{
    __shared__ int lc[NE];
    __shared__ int lb[NE];
    const int tid = threadIdx.x;
    if (tid < NE) lc[tid] = 0;
    __syncthreads();
    const int t = blockIdx.x * 256 + tid;
    const u32 ep = tokE[t];
    const float2 p = tokP[t];
    const int e0 = (int)(ep & 0xFFFFu), e1 = (int)(ep >> 16);
    const int q0 = atomicAdd(&lc[e0], 1);
    const int q1 = atomicAdd(&lc[e1], 1);
    __syncthreads();
    if (tid < NE) lb[tid] = atomicAdd(&cnt2[tid], lc[tid]);
    __syncthreads();
    const int r0 = offs[e0] + lb[e0] + q0;
    rowtok[r0] = t; rowp[r0] = p.x;
    const int r1 = offs[e1] + lb[e1] + q1;
    rowtok[r1] = t; rowp[r1] = p.y;
}

// -------------------------------------------------------------- transpose
// fp32 [E][R][C] -> bf16 [E][C][R]  (weights K-major -> N-major for MFMA B)
__global__ __launch_bounds__(256)
void transpose_kernel(const float* __restrict__ in, u16* __restrict__ out,
                      int R, int C)
{
    __shared__ float tile[32][33];
    const int e = blockIdx.z;
    const float* pin = in + (size_t)e * R * C;
    u16* pout = out + (size_t)e * R * C;
    const int c0 = blockIdx.x * 32, r0 = blockIdx.y * 32;
#pragma unroll
    for (int i = 0; i < 4; ++i) {
        const int r = threadIdx.y + i * 8;
        tile[r][threadIdx.x] = pin[(size_t)(r0 + r) * C + c0 + threadIdx.x];
    }
    __syncthreads();
#pragma unroll
    for (int i = 0; i < 4; ++i) {
        const int r = threadIdx.y + i * 8;
        pout[(size_t)(c0 + r) * R + r0 + threadIdx.x] = f2b(tile[threadIdx.x][r]);
    }
}

// ------------------------------------------------------------------ GEMM1
// h[row] = gelu(xb[tok(row)] @ w1[e] + b1[e]).  Round-3 register staging
// (loads issued before the barrier -> latency rides under prior MFMA burst)
// + XOR-swizzled LDS slots: global loads LINEAR (coalesced), LDS write addr
// swizzled (k8 ^ row&7), reads use round-4 swizzled indexing. Conflict-free
// at zero global-coalescing cost.  A-side is bf16 xb (no cvt VALU).
__global__ __launch_bounds__(256, 2)
void gemm1_kernel(const u16* __restrict__ xb, const u16* __restrict__ w1t,
                  const float* __restrict__ b1, const int* __restrict__ cnt,
                  const int* __restrict__ offs, const int* __restrict__ rowtok,
                  u16* __restrict__ h)
{
    const int e = blockIdx.z;
    const int ne = cnt[e];
    const int mt = blockIdx.y;
    if (mt * 128 >= ne) return;               // capacity grid, data-dependent exit
    const int nt = blockIdx.x;
    const int rowbase = offs[e] + mt * 128;

    __shared__ u16 lA[128 * 64];
    __shared__ u16 lB[128 * 64];

    const int tid = threadIdx.x;
    const int lane = tid & 63;

    const u16* wB = w1t + (size_t)e * HID * DIM + (size_t)nt * 128 * DIM;

    const u16* agp[4];
    const u16* bgp[4];
    int lslot[4];                              // swizzled LDS u16 offset
#pragma unroll
    for (int c = 0; c < 4; ++c) {
        const int lin = tid + c * 256;
        const int row = lin >> 3, k8 = lin & 7;
        const int tok = rowtok[rowbase + row];
        agp[c] = xb + (size_t)tok * DIM + k8 * 8;          // LINEAR global
        bgp[c] = wB + (size_t)row * DIM + k8 * 8;
        lslot[c] = (row * 8 + (k8 ^ (row & 7))) * 8;       // swizzled LDS
    }

    f32x4 acc[4][4];
#pragma unroll
    for (int i = 0; i < 4; ++i)
#pragma unroll
        for (int j = 0; j < 4; ++j)
            acc[i][j] = (f32x4){0.f, 0.f, 0.f, 0.f};

    const int wid = tid >> 6;
    const int wm = (wid >> 1) * 64;
    const int wn = (wid & 1) * 64;
    const int rsub = lane & 15;               // fragment row within 16-block
    const int sw = lane & 7;                  // = row&7 for fragment rows
    const int cq = lane >> 4;                 // k-chunk quad offset

    for (int k0 = 0; k0 < DIM; k0 += 64) {
        u16x8 ra[4], rb[4];
#pragma unroll
        for (int c = 0; c < 4; ++c) {
            ra[c] = *(const u16x8*)(agp[c] + k0);
            rb[c] = *(const u16x8*)(bgp[c] + k0);
        }
        __syncthreads();                        // prev iter's LDS reads done
#pragma unroll
        for (int c = 0; c < 4; ++c) {
            *(u16x8*)&lA[lslot[c]] = ra[c];
            *(u16x8*)&lB[lslot[c]] = rb[c];
        }
        __syncthreads();                        // staging visible
#pragma unroll
        for (int ks = 0; ks < 2; ++ks) {
            const int cc = ks * 4 + cq;         // k-chunk in the 64-window
            const int js = (cc ^ sw) * 8;       // swizzled slot offset (u16)
            bf16x8 av[4], bv[4];
#pragma unroll
            for (int f = 0; f < 4; ++f) {
                av[f] = *(const bf16x8*)&lA[(wm + f * 16 + rsub) * 64 + js];
                bv[f] = *(const bf16x8*)&lB[(wn + f * 16 + rsub) * 64 + js];
            }
#pragma unroll
            for (int i = 0; i < 4; ++i)
#pragma unroll
                for (int j = 0; j < 4; ++j)
                    acc[i][j] = __builtin_amdgcn_mfma_f32_16x16x32_bf16(
                        av[i], bv[j], acc[i][j], 0, 0, 0);
        }
    }

    // epilogue: C/D layout col=lane&15, row=(lane>>4)*4+reg (m89-verified)
    const int col = lane & 15;
    const int rq = (lane >> 4) * 4;
    const float* b1e = b1 + e * HID;
#pragma unroll
    for (int j = 0; j < 4; ++j) {
        const int hcol = nt * 128 + wn + j * 16 + col;
        const float bias = b1e[hcol];
#pragma unroll
        for (int i = 0; i < 4; ++i) {
            const int mrow = wm + i * 16 + rq;
#pragma unroll
            for (int r = 0; r < 4; ++r) {
                float v = acc[i][j][r] + bias;
                v = 0.5f * v * (1.f + erff(v * 0.70710678118f));   // exact gelu
                h[(size_t)(rowbase + mrow + r) * HID + hcol] = f2b(v);
            }
        }
    }
}

// ------------------------------------------------------------------ GEMM2
// (h[row] @ w2[e] + b2[e]) * p[row] -> atomicAdd fp32 directly into out.
__global__ __launch_bounds__(256, 2)
void gemm2_kernel(const u16* __restrict__ h, const u16* __restrict__ w2t,
                  const float* __restrict__ b2, const int* __restrict__ cnt,
                  const int* __restrict__ offs, const int* __restrict__ rowtok,
                  const float* __restrict__ rowp, float* __restrict__ outc)
{
    const int e = blockIdx.z;
    const int ne = cnt[e];
    const int mt = blockIdx.y;
    if (mt * 128 >= ne) return;
    const int nt = blockIdx.x;
    const int rowbase = offs[e] + mt * 128;

    __shared__ u16 lA[128 * 64];
    __shared__ u16 lB[128 * 64];

    const int tid = threadIdx.x;
    const int lane = tid & 63;

    const u16* wB = w2t + (size_t)e * DIM * HID + (size_t)nt * 128 * HID;

    const u16* agp[4];
    const u16* bgp[4];
    int lslot[4];
#pragma unroll
    for (int c = 0; c < 4; ++c) {
        const int lin = tid + c * 256;
        const int row = lin >> 3, k8 = lin & 7;
        agp[c] = h  + (size_t)(rowbase + row) * HID + k8 * 8;   // LINEAR global
        bgp[c] = wB + (size_t)row * HID + k8 * 8;
        lslot[c] = (row * 8 + (k8 ^ (row & 7))) * 8;            // swizzled LDS
    }

    f32x4 acc[4][4];
#pragma unroll
    for (int i = 0; i < 4; ++i)
#pragma unroll
        for (int j = 0; j < 4; ++j)
            acc[i][j] = (f32x4){0.f, 0.f, 0.f, 0.f};

    const int wid = tid >> 6;
    const int wm = (wid >> 1) * 64;
    const int wn = (wid & 1) * 64;
    const int rsub = lane & 15;
    const int sw = lane & 7;
    const int cq = lane >> 4;

    for (int k0 = 0; k0 < HID; k0 += 64) {
        u16x8 ra[4], rb[4];
#pragma unroll
        for (int c = 0; c < 4; ++c) {
            ra[c] = *(const u16x8*)(agp[c] + k0);
            rb[c] = *(const u16x8*)(bgp[c] + k0);
        }
        __syncthreads();
#pragma unroll
        for (int c = 0; c < 4; ++c) {
            *(u16x8*)&lA[lslot[c]] = ra[c];
            *(u16x8*)&lB[lslot[c]] = rb[c];
        }
        __syncthreads();
#pragma unroll
        for (int ks = 0; ks < 2; ++ks) {
            const int cc = ks * 4 + cq;
            const int js = (cc ^ sw) * 8;
            bf16x8 av[4], bv[4];
#pragma unroll
            for (int f = 0; f < 4; ++f) {
                av[f] = *(const bf16x8*)&lA[(wm + f * 16 + rsub) * 64 + js];
                bv[f] = *(const bf16x8*)&lB[(wn + f * 16 + rsub) * 64 + js];
            }
#pragma unroll
            for (int i = 0; i < 4; ++i)
#pragma unroll
                for (int j = 0; j < 4; ++j)
                    acc[i][j] = __builtin_amdgcn_mfma_f32_16x16x32_bf16(
                        av[i], bv[j], acc[i][j], 0, 0, 0);
        }
    }

    const int col = lane & 15;
    const int rq = (lane >> 4) * 4;
    const float* b2e = b2 + e * DIM;
    float biasv[4];
#pragma unroll
    for (int j = 0; j < 4; ++j)
        biasv[j] = b2e[nt * 128 + wn + j * 16 + col];
#pragma unroll
    for (int i = 0; i < 4; ++i) {
#pragma unroll
        for (int r = 0; r < 4; ++r) {
            const int rg = rowbase + wm + i * 16 + rq + r;
            const float p = rowp[rg];        // pad rows have p=0 -> adds 0
            const int tok = rowtok[rg];
            float* dst = outc + (size_t)tok * DIM + nt * 128 + wn + col;
#pragma unroll
            for (int j = 0; j < 4; ++j)
                atomicAdd(dst + j * 16, (acc[i][j][r] + biasv[j]) * p);
        }
    }
}

// ------------------------------------------------------------------ tail
__global__ void tail_kernel(const float* __restrict__ eload, float* __restrict__ out)
{
    if (threadIdx.x == 0) {
        float loss = 0.f;
        float le[NE];
#pragma unroll
        for (int e = 0; e < NE; ++e) {
            le[e] = eload[e] * (1.f / (float)NTOK);
            const float d = le[e] - 1.f / (float)NE;
            loss += d * d;
        }
        loss *= LB_W;
        out[(size_t)NTOK * DIM] = loss;
#pragma unroll
        for (int e = 0; e < NE; ++e)
            out[(size_t)NTOK * DIM + 1 + e] = le[e];
    }
}

// ------------------------------------------------------------------ launch
extern "C" void kernel_launch(void* const* d_in, const int* in_sizes, int n_in,
                              void* d_out, int out_size, void* d_ws, size_t ws_size,
                              hipStream_t stream)
{
    const float* x  = (const float*)d_in[0];
    const float* gw = (const float*)d_in[1];
    const float* gb = (const float*)d_in[2];
    const float* w1 = (const float*)d_in[3];
    const float* b1 = (const float*)d_in[4];
    const float* w2 = (const float*)d_in[5];
    const float* b2 = (const float*)d_in[6];
    float* out = (float*)d_out;
    char* ws = (char*)d_ws;

    // workspace layout (bytes), total ~281 MiB
    int*    cnt    = (int*)   (ws + 0);          // 32
    int*    cnt2   = (int*)   (ws + 32);         // 32
    int*    offs   = (int*)   (ws + 64);         // 32
    float*  eload  = (float*) (ws + 96);         // 32
    u32*    tokE   = (u32*)   (ws + 128);        // 32768
    float2* tokP   = (float2*)(ws + 32896);      // 65536
    int*    rowtok = (int*)   (ws + 98432);      // 69632
    float*  rowp   = (float*) (ws + 168064);     // 69632
    u16*    xb     = (u16*)   (ws + 237824);     // 16777216 (bf16 x)
    u16*    w1t    = (u16*)   (ws + 17015040);   // 67108864 (bf16)
    u16*    w2t    = (u16*)   (ws + 84123904);   // 67108864 (bf16)
    u16*    h      = (u16*)   (ws + 151232768);  // 142606336 (bf16)

    hipMemsetAsync(ws, 0, 128, stream);                                 // counters
    hipMemsetAsync(out, 0, (size_t)NTOK * DIM * sizeof(float), stream); // combine dst

    transpose_kernel<<<dim3(HID / 32, DIM / 32, NE), dim3(32, 8), 0, stream>>>(
        w1, w1t, DIM, HID);
    transpose_kernel<<<dim3(DIM / 32, HID / 32, NE), dim3(32, 8), 0, stream>>>(
        w2, w2t, HID, DIM);
    gate_kernel<<<NTOK / 32, 256, 0, stream>>>(x, gw, gb, tokE, tokP, cnt, eload, xb);
    offsets_kernel<<<1, 64, 0, stream>>>(cnt, offs, rowtok, rowp);
    scatter_kernel<<<NTOK / 256, 256, 0, stream>>>(tokE, tokP, offs, cnt2, rowtok, rowp);
    gemm1_kernel<<<dim3(HID / 128, 64, NE), 256, 0, stream>>>(
        xb, w1t, b1, cnt, offs, rowtok, h);
    gemm2_kernel<<<dim3(DIM / 128, 64, NE), 256, 0, stream>>>(
        h, w2t, b2, cnt, offs, rowtok, rowp, out);
    tail_kernel<<<1, 64, 0, stream>>>(eload, out);
}